// Round 11
// baseline (352.887 us; speedup 1.0000x reference)
//
#include <hip/hip_runtime.h>

typedef __bf16 bf16;
typedef __attribute__((ext_vector_type(8))) __bf16 bf16x8;
typedef __attribute__((ext_vector_type(4))) float f32x4;

#define T 128
#define DIM 4096
#define NACT 11468
#define A_PAD 11520
#define KO 512              // phase-1 panel: 512 f32 = 2KB per row
#define NP (DIM / KO)       // 8 panels
#define NCH 6
#define KCH (A_PAD / NCH)   // 1920
#define NC2 (KCH / 64)      // 30 chunks, phase 2

#define GLOAD16(src, dst)                                                          \
  __builtin_amdgcn_global_load_lds(                                                \
      (__attribute__((address_space(1))) const void*)(src),                        \
      (__attribute__((address_space(3))) void*)(dst), 16, 0, 0)

#define WAITCNT(n) asm volatile("s_waitcnt vmcnt(" #n ")" ::: "memory")
#define BAR() __builtin_amdgcn_s_barrier()

// ---------------- pre-kernel: x fp32 -> bf16 (plain layout) ----------------
__global__ __launch_bounds__(256) void k_cvt_x(const float* __restrict__ x,
                                               bf16* __restrict__ xb) {
  int i = (blockIdx.x * 256 + threadIdx.x) * 8;
  f32x4 a = *(const f32x4*)(x + i);
  f32x4 b = *(const f32x4*)(x + i + 4);
  bf16x8 o;
  o[0] = (bf16)a[0]; o[1] = (bf16)a[1]; o[2] = (bf16)a[2]; o[3] = (bf16)a[3];
  o[4] = (bf16)b[0]; o[5] = (bf16)b[1]; o[6] = (bf16)b[2]; o[7] = (bf16)b[3];
  *(bf16x8*)(xb + i) = o;
}

// ---------------- phase 1: g_e = silu(x w1^T) * (x w3^T) * ew_e ----------------
// Row-major mega-burst panels. Block: 256 t = 4 waves; BN=16 a-rows; per panel
// (KO=512 f32) stage w1[16][2KB] + w3[16][2KB] = 64KB LDS in ROW-MAJOR order:
// each wave bursts one row (2 back-to-back 1KB gload_lds), <=3 rows in flight
// (counted vmcnt) -> ~6K concurrent DRAM row-fronts chip-wide (~bank count)
// instead of ~46K -> page-hit streaming. Compute reads panel k-major from LDS
// (XOR swizzle, 4-way ok). Wave wv covers t-rows wv*32..+31 (no x duplication);
// x as direct per-lane B-frags from plain xb (r9-proven fragment conventions).
// 2 blocks/CU: one stages while the other computes.
__global__ __launch_bounds__(256, 2) void k_phase1(
    const bf16* __restrict__ xb,
    const float* __restrict__ w1e0, const float* __restrict__ w3e0,
    const float* __restrict__ w1e1, const float* __restrict__ w3e1,
    const float* __restrict__ ew, const int* __restrict__ ids,
    bf16* __restrict__ gws) {
  __shared__ __attribute__((aligned(16))) char smem[2][32768];  // [mat][16 rows x 2KB]
  const int e = blockIdx.y;
  const float* __restrict__ w1 = e ? w1e1 : w1e0;
  const float* __restrict__ w3 = e ? w3e1 : w3e0;
  bf16* __restrict__ g = gws + (size_t)e * T * A_PAD;

  const int tid = threadIdx.x;
  const int wv = tid >> 6;
  const int lane = tid & 63;
  const int ln = lane & 15;
  const int kh = lane >> 4;
  const int bx16 = blockIdx.x * 16;

  // Staging: wave wv -> mat (wv>>1), rows (wv&1)*8 .. +7 of the 16-row tile.
  const int mat = wv >> 1;
  const char* wmat = (const char*)(mat ? w3 : w1);
  const int rb = (wv & 1) * 8;

  // Per-row source base (global row clamped; pre-swizzled within each KB).
  const char* sb[8];
  char* db[8];
#pragma unroll
  for (int i = 0; i < 8; ++i) {
    const int r = rb + i;
    int grow = bx16 + r;
    grow = grow < NACT ? grow : NACT - 1;
    sb[i] = wmat + (size_t)grow * (DIM * 4) + ((lane * 16) ^ ((r & 7) << 4));
    db[i] = &smem[mat][0] + r * 2048 + lane * 16;
  }

  const bf16* __restrict__ px = xb + (size_t)(wv * 32 + ln) * DIM + kh * 8;
  const int xorl = (ln & 7) << 4;

  // acc[mat][nf]: D[16a][16t], a = kh*4+j, t = wv*32 + nf*16 + ln
  f32x4 accg[2], accu[2];
  accg[0] = (f32x4){0,0,0,0}; accg[1] = (f32x4){0,0,0,0};
  accu[0] = (f32x4){0,0,0,0}; accu[1] = (f32x4){0,0,0,0};

  bf16x8 xfA[8], xfB[8];

  // stage one row: two back-to-back 1KB loads (consecutive addresses)
#define SROW(i, p)                                                         \
  do {                                                                     \
    GLOAD16(sb[i] + (size_t)(p) * 2048, db[i]);                            \
    GLOAD16(sb[i] + (size_t)(p) * 2048 + 1024, db[i] + 1024);              \
  } while (0)

  auto XLOAD = [&](bf16x8 (&xf)[8], int p, int c) {
    const bf16* q = px + (size_t)p * KO + c * 128;
#pragma unroll
    for (int nf = 0; nf < 2; ++nf)
#pragma unroll
      for (int ks = 0; ks < 4; ++ks)
        xf[nf * 4 + ks] = *(const bf16x8*)(q + (size_t)nf * 16 * DIM + ks * 32);
  };
  auto COMPI = [&](const bf16x8 (&xf)[8], int c) {
#pragma unroll
    for (int ks4 = 0; ks4 < 4; ++ks4) {
      const int ko = (c * 4 + ks4) * 128 + kh * 32;
      bf16x8 wfr[2];
#pragma unroll
      for (int m = 0; m < 2; ++m) {
        const char* bp = &smem[m][0] + ln * 2048;
        f32x4 a0 = *(const f32x4*)(bp + (ko ^ xorl));
        f32x4 a1 = *(const f32x4*)(bp + ((ko + 16) ^ xorl));
        bf16x8 f;
        f[0] = (bf16)a0[0]; f[1] = (bf16)a0[1]; f[2] = (bf16)a0[2]; f[3] = (bf16)a0[3];
        f[4] = (bf16)a1[0]; f[5] = (bf16)a1[1]; f[6] = (bf16)a1[2]; f[7] = (bf16)a1[3];
        wfr[m] = f;
      }
#pragma unroll
      for (int nf = 0; nf < 2; ++nf) {
        accg[nf] = __builtin_amdgcn_mfma_f32_16x16x32_bf16(wfr[0], xf[nf * 4 + ks4], accg[nf], 0, 0, 0);
        accu[nf] = __builtin_amdgcn_mfma_f32_16x16x32_bf16(wfr[1], xf[nf * 4 + ks4], accu[nf], 0, 0, 0);
      }
    }
  };

  for (int p = 0; p < NP; ++p) {
    if (p > 0) BAR();            // prior panel's readers done -> LDS writable
    // row-major burst staging, <=3-4 rows in flight per wave
    SROW(0, p); SROW(1, p); SROW(2, p);
    WAITCNT(6); SROW(3, p);
    WAITCNT(6); SROW(4, p);
    WAITCNT(6); SROW(5, p);
    WAITCNT(6); SROW(6, p);
    WAITCNT(6); SROW(7, p);
    WAITCNT(0);                  // panel fully in LDS
    BAR();
    // compute: 4 inner chunks of 128k, x register-double-buffered
    XLOAD(xfA, p, 0);
    XLOAD(xfB, p, 1); WAITCNT(8); COMPI(xfA, 0);
    XLOAD(xfA, p, 2); WAITCNT(8); COMPI(xfB, 1);
    XLOAD(xfB, p, 3); WAITCNT(8); COMPI(xfA, 2);
    WAITCNT(0);                  COMPI(xfB, 3);
  }
#undef SROW

  // routing weights (swap if incoming expert_ids[0] != 0)
  float e0 = ew[0], e1 = ew[1];
  if (ids[0] != 0) { float t = e0; e0 = e1; e1 = t; }
  const float sel = e ? e1 : e0;

#pragma unroll
  for (int nf = 0; nf < 2; ++nf) {
    const int t = wv * 32 + nf * 16 + ln;
#pragma unroll
    for (int j = 0; j < 4; ++j) {
      const int a = bx16 + kh * 4 + j;   // D: row(a)=(lane>>4)*4+j, col(t)=lane&15
      float gt = accg[nf][j];
      float up = accu[nf][j];
      float sg = gt / (1.f + __expf(-gt));
      float val = (a < NACT) ? sg * up * sel : 0.f;  // zero-pad: phase 2 needs it
      g[(size_t)t * A_PAD + a] = (bf16)val;
    }
  }
}

// ---------------- phase 2: out += sum_e g_e @ w2_e  (split-K, atomic fp32) ----------------
// (unchanged — L3-warm and effectively free; keep verbatim)
__global__ __launch_bounds__(256, 2) void k_phase2(
    const bf16* __restrict__ gws,
    const float* __restrict__ w2e0, const float* __restrict__ w2e1,
    float* __restrict__ out) {
  __shared__ __attribute__((aligned(16))) char smem[2][32768];
  const int e = blockIdx.y / NCH;
  const int kc = blockIdx.y % NCH;
  const float* __restrict__ w2 = e ? w2e1 : w2e0;
  const bf16* __restrict__ g = gws + (size_t)e * T * A_PAD;

  const int tid = threadIdx.x;
  const int wv = tid >> 6;
  const int lane = tid & 63;
  const int ln = lane & 15;
  const int kh = lane >> 4;
  const int bx128 = blockIdx.x * 128;
  const int kcbase = kc * KCH;

  const bf16* __restrict__ pg = g + (size_t)(wv * 32 + ln) * A_PAD + kh * 8 + kcbase;

  f32x4 acc[2][8];
#pragma unroll
  for (int m = 0; m < 2; ++m)
#pragma unroll
    for (int n = 0; n < 8; ++n) acc[m][n] = (f32x4){0, 0, 0, 0};
  bf16x8 gf[2][2];

  auto STAGE2 = [&](int c, int b) {
    char* db = &smem[b][0] + (size_t)wv * 8192;
    const int kb = kcbase + c * 64;
#pragma unroll
    for (int i = 0; i < 8; ++i) {
      int kr = kb + (wv * 8 + i) * 2 + (lane >> 5);
      kr = kr < NACT ? kr : NACT - 1;  // dup row x g==0 pad -> 0 contribution
      const char* src = (const char*)w2 + ((size_t)kr * DIM + bx128) * 4 + (lane & 31) * 16;
      GLOAD16(src, db + i * 1024);
    }
  };
  auto GLOADG = [&](int c) {
    const bf16* p = pg + (size_t)c * 64;
#pragma unroll
    for (int m = 0; m < 2; ++m)
#pragma unroll
      for (int ks = 0; ks < 2; ++ks)
        gf[m][ks] = *(const bf16x8*)(p + (size_t)m * 16 * A_PAD + ks * 32);
  };
  auto COMP2 = [&](int b) {
    const char* base = &smem[b][0];
#pragma unroll
    for (int ks = 0; ks < 2; ++ks)
#pragma unroll
      for (int n = 0; n < 8; ++n) {
        bf16x8 wf;
#pragma unroll
        for (int j = 0; j < 8; ++j) {
          float f = *(const float*)(base + (ks * 32 + kh * 8 + j) * 512 + (n * 16 + ln) * 4);
          wf[j] = (bf16)f;
        }
#pragma unroll
        for (int m = 0; m < 2; ++m)
          acc[m][n] = __builtin_amdgcn_mfma_f32_16x16x32_bf16(gf[m][ks], wf, acc[m][n], 0, 0, 0);
      }
  };

  STAGE2(0, 0);
  for (int c = 0; c < NC2; ++c) {
    const int b = c & 1;
    GLOADG(c);         // outstanding: S(c)8 + g4
    WAITCNT(4);        // retire S(c); keep g
    BAR();
    if (c + 1 < NC2) {
      STAGE2(c + 1, b ^ 1);  // outstanding: g4 + S(c+1)8
      WAITCNT(8);            // retire g(c); keep S(c+1)
    } else {
      WAITCNT(0);
    }
    COMP2(b);
  }

  const int dbase = bx128 + ln;
#pragma unroll
  for (int m = 0; m < 2; ++m) {
#pragma unroll
    for (int n = 0; n < 8; ++n) {
#pragma unroll
      for (int j = 0; j < 4; ++j) {
        const int t = wv * 32 + m * 16 + kh * 4 + j;
        atomicAdd(out + (size_t)t * DIM + dbase + n * 16, acc[m][n][j]);
      }
    }
  }
}

// ---------------- launch ----------------
extern "C" void kernel_launch(void* const* d_in, const int* in_sizes, int n_in,
                              void* d_out, int out_size, void* d_ws, size_t ws_size,
                              hipStream_t stream) {
  const float* x    = (const float*)d_in[0];
  const float* ew   = (const float*)d_in[1];
  const int*   ids  = (const int*)d_in[2];
  const float* w1e0 = (const float*)d_in[3];
  const float* w3e0 = (const float*)d_in[4];
  const float* w2e0 = (const float*)d_in[5];
  const float* w1e1 = (const float*)d_in[6];
  const float* w3e1 = (const float*)d_in[7];
  const float* w2e1 = (const float*)d_in[8];
  float* out = (float*)d_out;

  bf16* xb = (bf16*)d_ws;                                   // 128*4096*2 = 1 MB
  bf16* g  = (bf16*)((char*)d_ws + (size_t)T * DIM * 2);    // 2 * 128*11520*2 = 5.9 MB

  hipMemsetAsync(d_out, 0, (size_t)T * DIM * sizeof(float), stream);
  k_cvt_x<<<dim3((T * DIM) / (256 * 8)), 256, 0, stream>>>(x, xb);
  k_phase1<<<dim3(A_PAD / 16, 2), 256, 0, stream>>>(xb, w1e0, w3e0, w1e1, w3e1, ew, ids, g);
  k_phase2<<<dim3(DIM / 128, 2 * NCH), 256, 0, stream>>>(g, w2e0, w2e1, out);
}

// Round 12
// 271.738 us; speedup vs baseline: 1.2986x; 1.2986x over previous
//
#include <hip/hip_runtime.h>

typedef __bf16 bf16;
typedef __attribute__((ext_vector_type(8))) __bf16 bf16x8;
typedef __attribute__((ext_vector_type(4))) float f32x4;

#define T 128
#define DIM 4096
#define NACT 11468
#define A_PAD 11520
#define BK1 128
#define NC1 (DIM / BK1)     // 32 chunks, phase 1
#define NCH 6
#define KCH (A_PAD / NCH)   // 1920
#define NC2 (KCH / 64)      // 30 chunks, phase 2

#define GLOAD16(src, dst)                                                          \
  __builtin_amdgcn_global_load_lds(                                                \
      (__attribute__((address_space(1))) const void*)(src),                        \
      (__attribute__((address_space(3))) void*)(dst), 16, 0, 0)

#define WAITCNT(n) asm volatile("s_waitcnt vmcnt(" #n ")" ::: "memory")
#define BAR() __builtin_amdgcn_s_barrier()

// ---------------- pre-kernel: x fp32 -> bf16 ----------------
__global__ __launch_bounds__(256) void k_cvt_x(const float* __restrict__ x,
                                               bf16* __restrict__ xb) {
  int i = (blockIdx.x * 256 + threadIdx.x) * 8;
  f32x4 a = *(const f32x4*)(x + i);
  f32x4 b = *(const f32x4*)(x + i + 4);
  bf16x8 o;
  o[0] = (bf16)a[0]; o[1] = (bf16)a[1]; o[2] = (bf16)a[2]; o[3] = (bf16)a[3];
  o[4] = (bf16)b[0]; o[5] = (bf16)b[1]; o[6] = (bf16)b[2]; o[7] = (bf16)b[3];
  *(bf16x8*)(xb + i) = o;
}

// ---------------- phase 1: g_e = silu(x w1^T) * (x w3^T) * ew_e ----------------
// CHAMPION (round-7 measured best: total 269.6 us, phase1 ~227 us).
// Block: 32 a-rows x 128 t. 4 waves, wave = M=32 t x N=32 a (2 mf x 2 nf frags).
// BK=128 -> 512B/row visit. LDS: 2 buf x 32KB (w1 32x512B | w3 32x512B),
// XOR-swizzled via pre-swizzled source. 2 blocks/CU. Per wave per chunk: 8 stage
// gload_lds + 8 x loads; x register-double-buffered, issued one chunk early
// (x-loads BEFORE stage-loads in queue so the x-wait does not drain staging).
__global__ __launch_bounds__(256, 2) void k_phase1(
    const bf16* __restrict__ xb,
    const float* __restrict__ w1e0, const float* __restrict__ w3e0,
    const float* __restrict__ w1e1, const float* __restrict__ w3e1,
    const float* __restrict__ ew, const int* __restrict__ ids,
    bf16* __restrict__ gws) {
  __shared__ __attribute__((aligned(16))) char smem[2][32768];
  const int e = blockIdx.y;
  const float* __restrict__ w1 = e ? w1e1 : w1e0;
  const float* __restrict__ w3 = e ? w3e1 : w3e0;
  bf16* __restrict__ g = gws + (size_t)e * T * A_PAD;

  const int tid = threadIdx.x;
  const int wv = tid >> 6;
  const int lane = tid & 63;
  const int ln = lane & 15;
  const int kh = lane >> 4;
  const int bx32 = blockIdx.x * 32;

  // staging: wave wv -> mat (wv>>1 ? w3 : w1), rows rb..rb+15; instr i covers
  // rows rb+i*2+(lane>>5), 512B each (one full BK-chunk span of that row)
  const char* wp = (const char*)((wv >> 1) ? w3 : w1);
  const int rb = (wv & 1) * 16;
  const int mo = (wv >> 1) * 16384;

  const char* sbase[8];
#pragma unroll
  for (int i = 0; i < 8; ++i) {
    const int row = rb + i * 2 + (lane >> 5);
    int grow = bx32 + row;
    grow = grow < NACT ? grow : NACT - 1;
    sbase[i] = wp + (size_t)grow * (DIM * 4) +
               (((lane & 31) * 16) ^ ((row & 7) << 4));  // pre-swizzled source
  }

  const bf16* __restrict__ px = xb + (size_t)(wv * 32 + ln) * DIM + kh * 8;
  const int swz = (ln & 7) << 4;

  f32x4 accu[2][2], accg[2][2];
#pragma unroll
  for (int mf = 0; mf < 2; ++mf)
#pragma unroll
    for (int nf = 0; nf < 2; ++nf) {
      accu[mf][nf] = (f32x4){0, 0, 0, 0};
      accg[mf][nf] = (f32x4){0, 0, 0, 0};
    }

  auto STAGE = [&](int c, int b) {
    char* db = &smem[b][0] + mo + rb * 512 + lane * 16;
    const size_t koff = (size_t)c * 512;
#pragma unroll
    for (int i = 0; i < 8; ++i) GLOAD16(sbase[i] + koff, db + i * 1024);
  };
  auto XLOAD = [&](bf16x8 (&xf)[8], int c) {
    const bf16* p = px + (size_t)c * BK1;
#pragma unroll
    for (int mf = 0; mf < 2; ++mf)
#pragma unroll
      for (int ks = 0; ks < 4; ++ks)
        xf[mf * 4 + ks] = *(const bf16x8*)(p + (size_t)mf * 16 * DIM + ks * 32);
  };
  auto COMP = [&](const bf16x8 (&xf)[8], int b) {
#pragma unroll
    for (int ks = 0; ks < 4; ++ks) {
      bf16x8 f1[2], f3[2];
#pragma unroll
      for (int nf = 0; nf < 2; ++nf) {
        const char* b1 = &smem[b][0] + (nf * 16 + ln) * 512;
        const char* b3 = b1 + 16384;
        const int o0 = (ks * 128 + kh * 32) ^ swz;
        const int o1 = (ks * 128 + kh * 32 + 16) ^ swz;
        f32x4 u0 = *(const f32x4*)(b1 + o0);
        f32x4 u1 = *(const f32x4*)(b1 + o1);
        f32x4 v0 = *(const f32x4*)(b3 + o0);
        f32x4 v1 = *(const f32x4*)(b3 + o1);
        f1[nf][0] = (bf16)u0[0]; f1[nf][1] = (bf16)u0[1];
        f1[nf][2] = (bf16)u0[2]; f1[nf][3] = (bf16)u0[3];
        f1[nf][4] = (bf16)u1[0]; f1[nf][5] = (bf16)u1[1];
        f1[nf][6] = (bf16)u1[2]; f1[nf][7] = (bf16)u1[3];
        f3[nf][0] = (bf16)v0[0]; f3[nf][1] = (bf16)v0[1];
        f3[nf][2] = (bf16)v0[2]; f3[nf][3] = (bf16)v0[3];
        f3[nf][4] = (bf16)v1[0]; f3[nf][5] = (bf16)v1[1];
        f3[nf][6] = (bf16)v1[2]; f3[nf][7] = (bf16)v1[3];
      }
#pragma unroll
      for (int mf = 0; mf < 2; ++mf)
#pragma unroll
        for (int nf = 0; nf < 2; ++nf) {
          accg[mf][nf] = __builtin_amdgcn_mfma_f32_16x16x32_bf16(xf[mf * 4 + ks], f1[nf], accg[mf][nf], 0, 0, 0);
          accu[mf][nf] = __builtin_amdgcn_mfma_f32_16x16x32_bf16(xf[mf * 4 + ks], f3[nf], accu[mf][nf], 0, 0, 0);
        }
    }
  };

  bf16x8 xfA[8], xfB[8];
  STAGE(0, 0);
  XLOAD(xfA, 0);

  for (int c = 0; c < NC1; c += 2) {
    // even chunk: x in A, buffer 0
    WAITCNT(8);                     // retire S(c); keep x(c)
    BAR();
    STAGE(c + 1, 1);
    XLOAD(xfB, c + 1);
    WAITCNT(16);                    // retire x(c); keep S(c+1)+x(c+1) in flight
    COMP(xfA, 0);
    // odd chunk: x in B, buffer 1
    WAITCNT(8);                     // retire S(c+1); keep x(c+1)
    BAR();
    if (c + 2 < NC1) {
      STAGE(c + 2, 0);
      XLOAD(xfA, c + 2);
      WAITCNT(16);                  // retire x(c+1)
    } else {
      WAITCNT(0);
    }
    COMP(xfB, 1);
  }

  // routing weights (swap if incoming expert_ids[0] != 0)
  float e0 = ew[0], e1 = ew[1];
  if (ids[0] != 0) { float t = e0; e0 = e1; e1 = t; }
  const float sel = e ? e1 : e0;

#pragma unroll
  for (int mf = 0; mf < 2; ++mf) {
#pragma unroll
    for (int nf = 0; nf < 2; ++nf) {
      const int a = bx32 + nf * 16 + ln;
      const bool valid = a < NACT;
#pragma unroll
      for (int j = 0; j < 4; ++j) {
        const int t = wv * 32 + mf * 16 + kh * 4 + j;  // C/D: row=(lane>>4)*4+j, col=lane&15
        float up = accu[mf][nf][j];
        float gt = accg[mf][nf][j];
        float sg = gt / (1.f + __expf(-gt));
        float val = valid ? sg * up * sel : 0.f;
        g[(size_t)t * A_PAD + a] = (bf16)val;
      }
    }
  }
}

// ---------------- phase 2: out += sum_e g_e @ w2_e  (split-K, atomic fp32) ----------------
// Block: 128 t x 128 d. 4 waves, wave = M=32 t x N=128 d. Chunk = 64 k-rows,
// each w2 row visited in 512B contiguous spans. LDS: 2 x 32KB [64k][128d] f32.
// Counted-vmcnt: per wave per chunk 8 stage gload_lds + 4 g loads.
__global__ __launch_bounds__(256, 2) void k_phase2(
    const bf16* __restrict__ gws,
    const float* __restrict__ w2e0, const float* __restrict__ w2e1,
    float* __restrict__ out) {
  __shared__ __attribute__((aligned(16))) char smem[2][32768];
  const int e = blockIdx.y / NCH;
  const int kc = blockIdx.y % NCH;
  const float* __restrict__ w2 = e ? w2e1 : w2e0;
  const bf16* __restrict__ g = gws + (size_t)e * T * A_PAD;

  const int tid = threadIdx.x;
  const int wv = tid >> 6;
  const int lane = tid & 63;
  const int ln = lane & 15;
  const int kh = lane >> 4;
  const int bx128 = blockIdx.x * 128;
  const int kcbase = kc * KCH;

  const bf16* __restrict__ pg = g + (size_t)(wv * 32 + ln) * A_PAD + kh * 8 + kcbase;

  f32x4 acc[2][8];
#pragma unroll
  for (int m = 0; m < 2; ++m)
#pragma unroll
    for (int n = 0; n < 8; ++n) acc[m][n] = (f32x4){0, 0, 0, 0};
  bf16x8 gf[2][2];

  auto STAGE2 = [&](int c, int b) {
    char* db = &smem[b][0] + (size_t)wv * 8192;
    const int kb = kcbase + c * 64;
#pragma unroll
    for (int i = 0; i < 8; ++i) {
      int kr = kb + (wv * 8 + i) * 2 + (lane >> 5);
      kr = kr < NACT ? kr : NACT - 1;  // dup row x g==0 pad -> 0 contribution
      const char* src = (const char*)w2 + ((size_t)kr * DIM + bx128) * 4 + (lane & 31) * 16;
      GLOAD16(src, db + i * 1024);
    }
  };
  auto GLOADG = [&](int c) {
    const bf16* p = pg + (size_t)c * 64;
#pragma unroll
    for (int m = 0; m < 2; ++m)
#pragma unroll
      for (int ks = 0; ks < 2; ++ks)
        gf[m][ks] = *(const bf16x8*)(p + (size_t)m * 16 * A_PAD + ks * 32);
  };
  auto COMP2 = [&](int b) {
    const char* base = &smem[b][0];
#pragma unroll
    for (int ks = 0; ks < 2; ++ks)
#pragma unroll
      for (int n = 0; n < 8; ++n) {
        bf16x8 wf;
#pragma unroll
        for (int j = 0; j < 8; ++j) {
          float f = *(const float*)(base + (ks * 32 + kh * 8 + j) * 512 + (n * 16 + ln) * 4);
          wf[j] = (bf16)f;
        }
#pragma unroll
        for (int m = 0; m < 2; ++m)
          acc[m][n] = __builtin_amdgcn_mfma_f32_16x16x32_bf16(gf[m][ks], wf, acc[m][n], 0, 0, 0);
      }
  };

  STAGE2(0, 0);
  for (int c = 0; c < NC2; ++c) {
    const int b = c & 1;
    GLOADG(c);         // outstanding: S(c)8 + g4
    WAITCNT(4);        // retire S(c); keep g
    BAR();
    if (c + 1 < NC2) {
      STAGE2(c + 1, b ^ 1);  // outstanding: g4 + S(c+1)8
      WAITCNT(8);            // retire g(c); keep S(c+1)
    } else {
      WAITCNT(0);
    }
    COMP2(b);
  }

  const int dbase = bx128 + ln;
#pragma unroll
  for (int m = 0; m < 2; ++m) {
#pragma unroll
    for (int n = 0; n < 8; ++n) {
#pragma unroll
      for (int j = 0; j < 4; ++j) {
        const int t = wv * 32 + m * 16 + kh * 4 + j;
        atomicAdd(out + (size_t)t * DIM + dbase + n * 16, acc[m][n][j]);
      }
    }
  }
}

// ---------------- launch ----------------
extern "C" void kernel_launch(void* const* d_in, const int* in_sizes, int n_in,
                              void* d_out, int out_size, void* d_ws, size_t ws_size,
                              hipStream_t stream) {
  const float* x    = (const float*)d_in[0];
  const float* ew   = (const float*)d_in[1];
  const int*   ids  = (const int*)d_in[2];
  const float* w1e0 = (const float*)d_in[3];
  const float* w3e0 = (const float*)d_in[4];
  const float* w2e0 = (const float*)d_in[5];
  const float* w1e1 = (const float*)d_in[6];
  const float* w3e1 = (const float*)d_in[7];
  const float* w2e1 = (const float*)d_in[8];
  float* out = (float*)d_out;

  bf16* xb = (bf16*)d_ws;                                   // 128*4096*2 = 1 MB
  bf16* g  = (bf16*)((char*)d_ws + (size_t)T * DIM * 2);    // 2 * 128*11520*2 = 5.9 MB

  hipMemsetAsync(d_out, 0, (size_t)T * DIM * sizeof(float), stream);
  k_cvt_x<<<dim3((T * DIM) / (256 * 8)), 256, 0, stream>>>(x, xb);
  k_phase1<<<dim3(A_PAD / 32, 2), 256, 0, stream>>>(xb, w1e0, w3e0, w1e1, w3e1, ew, ids, g);
  k_phase2<<<dim3(DIM / 128, 2 * NCH), 256, 0, stream>>>(g, w2e0, w2e1, out);
}